// Round 3
// baseline (659.849 us; speedup 1.0000x reference)
//
#include <hip/hip_runtime.h>

typedef __attribute__((ext_vector_type(8))) short short8;
typedef __attribute__((ext_vector_type(4))) float f32x4;

#define HH 256
#define WW 256

__device__ inline unsigned int f2bf(float x) {
  unsigned int u = __float_as_uint(x);
  return (u + 0x7fffu + ((u >> 16) & 1u)) >> 16;   // RTNE truncation to bf16
}
__device__ inline unsigned int pack2(float a, float b) {
  return f2bf(a) | (f2bf(b) << 16);
}

// ---------------- transpose x (fp32 NCHW) -> xcl bf16 [B][H][W][64] ----------------
__global__ __launch_bounds__(256) void xpose_k(const float* __restrict__ x,
                                               unsigned short* __restrict__ xcl) {
  const int t = threadIdx.x;
  const int ci = t & 63;
  const int wv = t >> 6;
  const int x0 = blockIdx.x * 64;
  const int y  = blockIdx.y;
  const int b  = blockIdx.z;
  const float* src = x + ((size_t)(b * 64 + ci) * HH + y) * WW + x0 + wv;
  unsigned short* dst = xcl + ((size_t)(b * HH + y) * WW + x0 + wv) * 64 + ci;
#pragma unroll
  for (int k = 0; k < 16; ++k)
    dst[(size_t)k * 4 * 64] = (unsigned short)f2bf(src[4 * k]);
}

// ---------------- weight norm -> [tap][co][ci] bf16 ----------------
template <int COUT, int CINK>
__global__ __launch_bounds__(256) void wnorm_k(const float* __restrict__ v,
                                               const float* __restrict__ g,
                                               unsigned short* __restrict__ out) {
  constexpr int N = CINK * 9;
  const int co = blockIdx.x, t = threadIdx.x;
  const float* vb = v + (size_t)co * N;
  float s = 0.f;
  for (int i = t; i < N; i += 256) { float a = vb[i]; s += a * a; }
  for (int off = 32; off > 0; off >>= 1) s += __shfl_xor(s, off, 64);
  __shared__ float red[4];
  if ((t & 63) == 0) red[t >> 6] = s;
  __syncthreads();
  const float tot = red[0] + red[1] + red[2] + red[3];
  const float sc = g[co] / sqrtf(tot);
  for (int i = t; i < N; i += 256) {
    int ci = i / 9, tap = i - 9 * (i / 9);
    out[((size_t)tap * COUT + co) * CINK + ci] = (unsigned short)f2bf(vb[i] * sc);
  }
}

// ---------------- dyn bank norms ----------------
__global__ __launch_bounds__(256) void dynnorm_k(const float* __restrict__ dyn_v,
                                                 const float* __restrict__ dyn_g,
                                                 float* __restrict__ dscale) {
  const int k = blockIdx.x, t = threadIdx.x;
  const float* vb = dyn_v + (size_t)k * 36864;
  float s = 0.f;
  for (int i = t; i < 36864; i += 256) { float a = vb[i]; s += a * a; }
  for (int off = 32; off > 0; off >>= 1) s += __shfl_xor(s, off, 64);
  __shared__ float red[4];
  if ((t & 63) == 0) red[t >> 6] = s;
  __syncthreads();
  if (t == 0) dscale[k] = dyn_g[k] / sqrtf(red[0] + red[1] + red[2] + red[3]);
}

// ---------------- per-sample mixed dyn weights + bias; zero the zero-page ----------------
__global__ __launch_bounds__(256) void mix_k(const float* __restrict__ scale,
                                             const float* __restrict__ att_w,
                                             const float* __restrict__ att_b,
                                             const float* __restrict__ dyn_v,
                                             const float* __restrict__ dyn_b,
                                             const float* __restrict__ dscale,
                                             unsigned short* __restrict__ wbt,
                                             float* __restrict__ bias_b,
                                             float* __restrict__ zp) {
  const int blk = blockIdx.x;
  const int b = blk >> 6, co = blk & 63;
  const int t = threadIdx.x;
  float att[4], wsc[4];
  const float sc = scale[b];
  float mx = -1e30f;
#pragma unroll
  for (int k = 0; k < 4; ++k) { att[k] = sc * att_w[k] + att_b[k]; mx = fmaxf(mx, att[k]); }
  float den = 0.f;
#pragma unroll
  for (int k = 0; k < 4; ++k) { att[k] = expf(att[k] - mx); den += att[k]; }
#pragma unroll
  for (int k = 0; k < 4; ++k) { att[k] /= den; wsc[k] = att[k] * dscale[k]; }
  for (int i = t; i < 576; i += 256) {
    int ci = i / 9, tap = i - 9 * (i / 9);
    float w = 0.f;
#pragma unroll
    for (int k = 0; k < 4; ++k)
      w += wsc[k] * dyn_v[(((size_t)k * 64 + co) * 64 + ci) * 9 + tap];
    wbt[(((size_t)b * 9 + tap) * 64 + co) * 64 + ci] = (unsigned short)f2bf(w);
  }
  if (t == 0) {
    float bb = 0.f;
#pragma unroll
    for (int k = 0; k < 4; ++k) bb += att[k] * dyn_b[k * 64 + co];
    bias_b[blk] = bb;
  }
  if (blk == 0 && t < 32) zp[t] = 0.f;
}

// ---------------- MFMA 3x3 conv v3: gload_lds staging, chunk=32, 4 blocks/CU ----------------
// LDS layout: slot(px, g) at byte px*64 + g*16, px = row*34+col (10x34 halo tile),
// slot (px,g) holds ci-group (g ^ (col&3)) of 8 bf16. Stage: linear LDS dest
// (wave base + lane*16) + XOR applied to the GLOBAL source address (rule-21 involution).
// Read: byte = px*64 + ((lg*16) ^ ((col&3)<<4)) -> retrieves ci-group lg. 8 lanes per
// 16B bank-slot class -> conflict-free b128.
template <int CIN, int COUT, int OSTR, bool RELU, bool DYN>
__global__ __launch_bounds__(256, 4) void conv3x3_mfma(const unsigned short* __restrict__ in_cl,
                                                       const unsigned short* __restrict__ wt,
                                                       const float* __restrict__ bias,
                                                       unsigned short* __restrict__ out_cl,
                                                       float* __restrict__ y_out,
                                                       float* __restrict__ pblk,
                                                       const float* __restrict__ zp) {
  constexpr int CO_TILES = COUT / 64;
  const int tid = threadIdx.x;
  const int lane = tid & 63;
  const int wv = tid >> 6;
  const int l15 = lane & 15;
  const int lg = lane >> 4;
  const int cot = blockIdx.z % CO_TILES;
  const int bz = blockIdx.z / CO_TILES;
  const int x0 = blockIdx.x * 32;
  const int y0 = blockIdx.y * 8;
  const int co0 = cot * 64;

  const unsigned short* inb = in_cl + (size_t)bz * HH * WW * CIN;
  const unsigned short* wtb = wt + (DYN ? (size_t)bz * 9 * 64 * 64 : (size_t)0);
  const float* biasb = bias + (DYN ? bz * 64 : 0);

  __shared__ unsigned short tile[11264];  // 1408 slots * 16B = 22528 B

  f32x4 acc[4][4];
#pragma unroll
  for (int m = 0; m < 4; ++m)
#pragma unroll
    for (int n = 0; n < 4; ++n) acc[m][n] = (f32x4){0.f, 0.f, 0.f, 0.f};

#pragma unroll 1
  for (int chunk = 0; chunk < CIN / 32; ++chunk) {
    if (chunk) __syncthreads();
    // ---- stage 10x34 halo x 32ci via global_load_lds (1360 real slots, pad to 1408) ----
#pragma unroll
    for (int k = 0; k < 6; ++k) {
      const int u = k * 256 + tid;
      if (u < 1408) {
        const int px = u >> 2;
        const int g = u & 3;
        const int col = px % 34;
        const int row = px / 34;
        const int gyy = y0 - 1 + row;
        const int gxx = x0 - 1 + col;
        const int gsw = g ^ (col & 3);  // source-side swizzle (involution)
        const bool ok = (u < 1360) && ((unsigned)gyy < (unsigned)HH) &&
                        ((unsigned)gxx < (unsigned)WW);
        const void* src = ok ? (const void*)(inb + ((size_t)(gyy * WW + gxx)) * CIN +
                                             chunk * 32 + gsw * 8)
                             : (const void*)zp;
        unsigned short* ldsb = tile + (size_t)(k * 256 + wv * 64) * 8;  // wave-uniform
        __builtin_amdgcn_global_load_lds(src, (void*)ldsb, 16, 0, 0);
      }
    }
    __syncthreads();
    // ---- compute: 9 taps x {4 A-loads, 4 B ds_reads, 16 MFMA} ----
#pragma unroll
    for (int tap = 0; tap < 9; ++tap) {
      const int dy = tap / 3;
      const int dx = tap - 3 * dy;
      short8 A[4], Bv[4];
#pragma unroll
      for (int m = 0; m < 4; ++m)
        A[m] = *(const short8*)(wtb + (((size_t)tap * COUT + co0 + 16 * m + l15) * CIN +
                                       chunk * 32 + lg * 8));
#pragma unroll
      for (int n = 0; n < 4; ++n) {
        const int brow = 2 * wv + (n >> 1) + dy;
        const int bcol = 16 * (n & 1) + l15 + dx;
        const int byt = (brow * 34 + bcol) * 64 + ((lg * 16) ^ ((bcol & 3) << 4));
        Bv[n] = *(const short8*)((const char*)tile + byt);
      }
      __builtin_amdgcn_s_setprio(1);
#pragma unroll
      for (int n = 0; n < 4; ++n)
#pragma unroll
        for (int m = 0; m < 4; ++m)
          acc[m][n] = __builtin_amdgcn_mfma_f32_16x16x32_bf16(A[m], Bv[n], acc[m][n], 0, 0, 0);
      __builtin_amdgcn_s_setprio(0);
    }
  }

  float scol[4][4];
  if (DYN) {
#pragma unroll
    for (int m = 0; m < 4; ++m)
#pragma unroll
      for (int f = 0; f < 4; ++f) scol[m][f] = 0.f;
  }

#pragma unroll
  for (int m = 0; m < 4; ++m) {
    const f32x4 bs = *(const f32x4*)(biasb + co0 + 16 * m + 4 * lg);
#pragma unroll
    for (int n = 0; n < 4; ++n) {
      f32x4 v = acc[m][n] + bs;
      if (RELU) {
        v.x = fmaxf(v.x, 0.f); v.y = fmaxf(v.y, 0.f);
        v.z = fmaxf(v.z, 0.f); v.w = fmaxf(v.w, 0.f);
      }
      const int yy = y0 + 2 * wv + (n >> 1);
      const int xx = x0 + 16 * (n & 1) + l15;
      if (!DYN) {
        uint2 pk;
        pk.x = pack2(v.x, v.y);
        pk.y = pack2(v.z, v.w);
        *(uint2*)(out_cl + (size_t)bz * HH * WW * OSTR +
                  ((size_t)(yy * WW + xx)) * OSTR + co0 + 16 * m + 4 * lg) = pk;
      } else {
        const size_t base = ((size_t)(bz * 64 + 16 * m + 4 * lg) * HH + yy) * WW + xx;
        y_out[base]             = v.x;
        y_out[base + 1 * 65536] = v.y;
        y_out[base + 2 * 65536] = v.z;
        y_out[base + 3 * 65536] = v.w;
        scol[m][0] += v.x; scol[m][1] += v.y; scol[m][2] += v.z; scol[m][3] += v.w;
      }
    }
  }
  if (DYN) {
#pragma unroll
    for (int m = 0; m < 4; ++m)
#pragma unroll
      for (int f = 0; f < 4; ++f) {
        float r = scol[m][f];
        r += __shfl_xor(r, 1, 64);
        r += __shfl_xor(r, 2, 64);
        r += __shfl_xor(r, 4, 64);
        r += __shfl_xor(r, 8, 64);
        scol[m][f] = r;
      }
    __syncthreads();  // tile dead; reuse as fp32 scratch
    float* red = (float*)tile;
    if (l15 == 0) {
#pragma unroll
      for (int m = 0; m < 4; ++m)
#pragma unroll
        for (int f = 0; f < 4; ++f)
          red[wv * 64 + 16 * m + 4 * lg + f] = scol[m][f];
    }
    __syncthreads();
    if (tid < 64) {
      const float s = red[tid] + red[64 + tid] + red[128 + tid] + red[192 + tid];
      pblk[((size_t)bz * 256 + blockIdx.y * 8 + blockIdx.x) * 64 + tid] = s;
    }
  }
}

// ---------------- SE gate: 4 blocks (one per sample) ----------------
__global__ __launch_bounds__(256) void gate_k(const float* __restrict__ pblk,
                                              const float* __restrict__ se_w1,
                                              const float* __restrict__ se_w2,
                                              float* __restrict__ gate) {
  const int b = blockIdx.x;
  const int t = threadIdx.x;
  const int c = t & 63, part = t >> 6;
  __shared__ float ps[4][64];
  __shared__ float p_s[64], h_s[16];
  float s = 0.f;
  for (int blk = part; blk < 256; blk += 4)
    s += pblk[((size_t)b * 256 + blk) * 64 + c];
  ps[part][c] = s;
  __syncthreads();
  if (t < 64) p_s[t] = (ps[0][t] + ps[1][t] + ps[2][t] + ps[3][t]) * (1.f / 65536.f);
  __syncthreads();
  if (t < 16) {
    float h = 0.f;
    for (int cc = 0; cc < 64; ++cc) h += p_s[cc] * se_w1[t * 64 + cc];
    h_s[t] = fmaxf(h, 0.f);
  }
  __syncthreads();
  if (t < 64) {
    float a = 0.f;
    for (int j = 0; j < 16; ++j) a += h_s[j] * se_w2[t * 16 + j];
    gate[b * 64 + t] = 1.f / (1.f + expf(-a));
  }
}

// ---------------- final: out = x + y*gate (in-place on d_out) ----------------
__global__ __launch_bounds__(256) void final_k(const float* __restrict__ x,
                                               const float* __restrict__ gate,
                                               float* __restrict__ out) {
  const size_t i = ((size_t)blockIdx.x * 256 + threadIdx.x) * 4;
  f32x4 yv = *(f32x4*)(out + i);
  const f32x4 xv = *(const f32x4*)(x + i);
  const float g = gate[(int)(i >> 16)];
  yv = xv + yv * g;
  *(f32x4*)(out + i) = yv;
}

// ---------------- workspace layout (batched) ----------------
static constexpr size_t SZ_XCL = (size_t)4 * 256 * 256 * 64 * 2;   // 33.55 MB
static constexpr size_t SZ_W   = (size_t)9 * 256 * 64 * 2;         // 294912
static constexpr size_t SZ_PBLK = (size_t)4 * 256 * 64 * 4;        // 262144

static constexpr size_t B_XCL = 0;                                 // also r2 (aliased)
static constexpr size_t B_R   = B_XCL + SZ_XCL;
static constexpr size_t B_W1T = B_R + 4 * SZ_XCL;                  // 134.2 MB of r
static constexpr size_t B_W2T = B_W1T + SZ_W;
static constexpr size_t B_WBT = B_W2T + SZ_W;
static constexpr size_t B_DSC = B_WBT + SZ_W;
static constexpr size_t B_BB  = B_DSC + 256;
static constexpr size_t B_GT  = B_BB + 1024;
static constexpr size_t B_ZP  = B_GT + 1024;
static constexpr size_t B_PBLK = B_ZP + 1024;
static constexpr size_t WS_BIG = B_PBLK + SZ_PBLK;

extern "C" void kernel_launch(void* const* d_in, const int* in_sizes, int n_in,
                              void* d_out, int out_size, void* d_ws, size_t ws_size,
                              hipStream_t stream) {
  (void)in_sizes; (void)n_in; (void)out_size;
  if (ws_size < WS_BIG) return;  // ~169 MB scratch required (harness provides it)

  const float* x     = (const float*)d_in[0];
  const float* scale = (const float*)d_in[1];
  const float* v1    = (const float*)d_in[2];
  const float* g1    = (const float*)d_in[3];
  const float* b1    = (const float*)d_in[4];
  const float* v2    = (const float*)d_in[5];
  const float* g2    = (const float*)d_in[6];
  const float* b2    = (const float*)d_in[7];
  const float* dyn_v = (const float*)d_in[8];
  const float* dyn_g = (const float*)d_in[9];
  const float* dyn_b = (const float*)d_in[10];
  const float* att_w = (const float*)d_in[11];
  const float* att_b = (const float*)d_in[12];
  const float* se_w1 = (const float*)d_in[13];
  const float* se_w2 = (const float*)d_in[14];
  float* out = (float*)d_out;

  char* ws = (char*)d_ws;
  unsigned short* xcl  = (unsigned short*)(ws + B_XCL);
  unsigned short* rbuf = (unsigned short*)(ws + B_R);
  unsigned short* r2   = (unsigned short*)(ws + B_XCL);  // aliases dead xcl
  unsigned short* w1t  = (unsigned short*)(ws + B_W1T);
  unsigned short* w2t  = (unsigned short*)(ws + B_W2T);
  unsigned short* wbt  = (unsigned short*)(ws + B_WBT);
  float* dscale = (float*)(ws + B_DSC);
  float* bias_b = (float*)(ws + B_BB);
  float* gate   = (float*)(ws + B_GT);
  float* zp     = (float*)(ws + B_ZP);
  float* pblk   = (float*)(ws + B_PBLK);

  xpose_k<<<dim3(4, 256, 4), 256, 0, stream>>>(x, xcl);
  wnorm_k<256, 64><<<256, 256, 0, stream>>>(v1, g1, w1t);
  wnorm_k<64, 256><<<64, 256, 0, stream>>>(v2, g2, w2t);
  dynnorm_k<<<4, 256, 0, stream>>>(dyn_v, dyn_g, dscale);
  mix_k<<<256, 256, 0, stream>>>(scale, att_w, att_b, dyn_v, dyn_b, dscale, wbt, bias_b, zp);

  conv3x3_mfma<64, 256, 256, true, false><<<dim3(8, 32, 16), 256, 0, stream>>>(
      xcl, w1t, b1, rbuf, nullptr, nullptr, zp);
  conv3x3_mfma<256, 64, 64, false, false><<<dim3(8, 32, 4), 256, 0, stream>>>(
      rbuf, w2t, b2, r2, nullptr, nullptr, zp);
  conv3x3_mfma<64, 64, 64, false, true><<<dim3(8, 32, 4), 256, 0, stream>>>(
      r2, wbt, bias_b, nullptr, out, pblk, zp);

  gate_k<<<4, 256, 0, stream>>>(pblk, se_w1, se_w2, gate);
  final_k<<<16384, 256, 0, stream>>>(x, gate, out);
}

// Round 4
// 511.223 us; speedup vs baseline: 1.2907x; 1.2907x over previous
//
#include <hip/hip_runtime.h>

typedef __attribute__((ext_vector_type(8))) short short8;
typedef __attribute__((ext_vector_type(4))) float f32x4;

#define HH 256
#define WW 256

__device__ inline unsigned int f2bf(float x) {
  unsigned int u = __float_as_uint(x);
  return (u + 0x7fffu + ((u >> 16) & 1u)) >> 16;   // RTNE truncation to bf16
}
__device__ inline unsigned int pack2(float a, float b) {
  return f2bf(a) | (f2bf(b) << 16);
}

// ---------------- transpose x (fp32 NCHW) -> xcl bf16 [B][H][W][64] ----------------
__global__ __launch_bounds__(256) void xpose_k(const float* __restrict__ x,
                                               unsigned short* __restrict__ xcl) {
  const int t = threadIdx.x;
  const int ci = t & 63;
  const int wv = t >> 6;
  const int x0 = blockIdx.x * 64;
  const int y  = blockIdx.y;
  const int b  = blockIdx.z;
  const float* src = x + ((size_t)(b * 64 + ci) * HH + y) * WW + x0 + wv;
  unsigned short* dst = xcl + ((size_t)(b * HH + y) * WW + x0 + wv) * 64 + ci;
#pragma unroll
  for (int k = 0; k < 16; ++k)
    dst[(size_t)k * 4 * 64] = (unsigned short)f2bf(src[4 * k]);
}

// ---------------- weight norm -> [tap][co][ci] bf16 ----------------
template <int COUT, int CINK>
__global__ __launch_bounds__(256) void wnorm_k(const float* __restrict__ v,
                                               const float* __restrict__ g,
                                               unsigned short* __restrict__ out) {
  constexpr int N = CINK * 9;
  const int co = blockIdx.x, t = threadIdx.x;
  const float* vb = v + (size_t)co * N;
  float s = 0.f;
  for (int i = t; i < N; i += 256) { float a = vb[i]; s += a * a; }
  for (int off = 32; off > 0; off >>= 1) s += __shfl_xor(s, off, 64);
  __shared__ float red[4];
  if ((t & 63) == 0) red[t >> 6] = s;
  __syncthreads();
  const float tot = red[0] + red[1] + red[2] + red[3];
  const float sc = g[co] / sqrtf(tot);
  for (int i = t; i < N; i += 256) {
    int ci = i / 9, tap = i - 9 * (i / 9);
    out[((size_t)tap * COUT + co) * CINK + ci] = (unsigned short)f2bf(vb[i] * sc);
  }
}

// ---------------- dyn bank norms ----------------
__global__ __launch_bounds__(256) void dynnorm_k(const float* __restrict__ dyn_v,
                                                 const float* __restrict__ dyn_g,
                                                 float* __restrict__ dscale) {
  const int k = blockIdx.x, t = threadIdx.x;
  const float* vb = dyn_v + (size_t)k * 36864;
  float s = 0.f;
  for (int i = t; i < 36864; i += 256) { float a = vb[i]; s += a * a; }
  for (int off = 32; off > 0; off >>= 1) s += __shfl_xor(s, off, 64);
  __shared__ float red[4];
  if ((t & 63) == 0) red[t >> 6] = s;
  __syncthreads();
  if (t == 0) dscale[k] = dyn_g[k] / sqrtf(red[0] + red[1] + red[2] + red[3]);
}

// ---------------- per-sample mixed dyn weights + bias ----------------
__global__ __launch_bounds__(256) void mix_k(const float* __restrict__ scale,
                                             const float* __restrict__ att_w,
                                             const float* __restrict__ att_b,
                                             const float* __restrict__ dyn_v,
                                             const float* __restrict__ dyn_b,
                                             const float* __restrict__ dscale,
                                             unsigned short* __restrict__ wbt,
                                             float* __restrict__ bias_b) {
  const int blk = blockIdx.x;
  const int b = blk >> 6, co = blk & 63;
  const int t = threadIdx.x;
  float att[4], wsc[4];
  const float sc = scale[b];
  float mx = -1e30f;
#pragma unroll
  for (int k = 0; k < 4; ++k) { att[k] = sc * att_w[k] + att_b[k]; mx = fmaxf(mx, att[k]); }
  float den = 0.f;
#pragma unroll
  for (int k = 0; k < 4; ++k) { att[k] = expf(att[k] - mx); den += att[k]; }
#pragma unroll
  for (int k = 0; k < 4; ++k) { att[k] /= den; wsc[k] = att[k] * dscale[k]; }
  for (int i = t; i < 576; i += 256) {
    int ci = i / 9, tap = i - 9 * (i / 9);
    float w = 0.f;
#pragma unroll
    for (int k = 0; k < 4; ++k)
      w += wsc[k] * dyn_v[(((size_t)k * 64 + co) * 64 + ci) * 9 + tap];
    wbt[(((size_t)b * 9 + tap) * 64 + co) * 64 + ci] = (unsigned short)f2bf(w);
  }
  if (t == 0) {
    float bb = 0.f;
#pragma unroll
    for (int k = 0; k < 4; ++k) bb += att[k] * dyn_b[k * 64 + co];
    bias_b[blk] = bb;
  }
}

// ---------------- MFMA 3x3 conv v4 ----------------
// Block: 64co x 16rows x 32cols. 4 waves stacked in rows; wave = m4 (64co) x n8 (4r x 2colhalf).
// ci-chunk = 32. LDS halo tile 18x34 px x 32ci bf16 = 39168 B, stored with the PROVEN
// 128B-row swizzle using pixel-pairs as rows:
//   byte(px,lg) = (px>>1)*128 + ((lg*16 + (px&1)*64) ^ (((px>>1)&7)<<4))
// Staging is reg-staged (10 uint4/thread) with T14 issue-early/write-late across chunks.
template <int CIN, int COUT, int OSTR, bool RELU, bool DYN>
__global__ __launch_bounds__(256, 2) void conv3x3_mfma(const unsigned short* __restrict__ in_cl,
                                                       const unsigned short* __restrict__ wt,
                                                       const float* __restrict__ bias,
                                                       unsigned short* __restrict__ out_cl,
                                                       float* __restrict__ y_out,
                                                       float* __restrict__ pblk) {
  constexpr int CO_TILES = COUT / 64;
  constexpr int NCH = CIN / 32;
  constexpr int NSLOT = 612 * 4;  // 18*34 px * 4 lg-groups
  const int tid = threadIdx.x;
  const int lane = tid & 63;
  const int wv = tid >> 6;
  const int l15 = lane & 15;
  const int lg = lane >> 4;
  const int cot = blockIdx.z % CO_TILES;
  const int bz = blockIdx.z / CO_TILES;
  const int x0 = blockIdx.x * 32;
  const int y0 = blockIdx.y * 16;
  const int co0 = cot * 64;

  const unsigned short* inb = in_cl + (size_t)bz * HH * WW * CIN;
  const unsigned short* wtb = wt + (DYN ? (size_t)bz * 9 * 64 * 64 : (size_t)0);
  const float* biasb = bias + (DYN ? bz * 64 : 0);

  __shared__ unsigned short tile[NSLOT * 8];  // 39168 B

  // ---- precompute per-thread staging slots ----
  const unsigned short* sptr[10];
  int sbyte[10];
  bool sok[10], sw[10];
#pragma unroll
  for (int k = 0; k < 10; ++k) {
    const int u = k * 256 + tid;
    const int px = u >> 2, g = u & 3;
    const int row = px / 34, col = px - 34 * row;
    const int gy = y0 - 1 + row, gx = x0 - 1 + col;
    sw[k] = (u < NSLOT);
    sok[k] = sw[k] && ((unsigned)gy < (unsigned)HH) && ((unsigned)gx < (unsigned)WW);
    sptr[k] = inb + (sok[k] ? ((size_t)(gy * WW + gx)) * CIN + g * 8 : (size_t)0);
    sbyte[k] = (px >> 1) * 128 + ((g * 16 + (px & 1) * 64) ^ (((px >> 1) & 7) << 4));
  }

  f32x4 acc[4][8];
#pragma unroll
  for (int m = 0; m < 4; ++m)
#pragma unroll
    for (int n = 0; n < 8; ++n) acc[m][n] = (f32x4){0.f, 0.f, 0.f, 0.f};

  // preload chunk 0
  uint4 sv[10];
#pragma unroll
  for (int k = 0; k < 10; ++k) {
    uint4 v = {0u, 0u, 0u, 0u};
    if (sok[k]) v = *(const uint4*)(sptr[k]);
    sv[k] = v;
  }

#pragma unroll 1
  for (int ch = 0; ch < NCH; ++ch) {
    if (ch) __syncthreads();  // previous chunk's compute done before overwrite
#pragma unroll
    for (int k = 0; k < 10; ++k)
      if (sw[k]) *(uint4*)((char*)tile + sbyte[k]) = sv[k];
    __syncthreads();
    if (ch + 1 < NCH) {  // issue next chunk's loads early (T14)
#pragma unroll
      for (int k = 0; k < 10; ++k) {
        uint4 v = {0u, 0u, 0u, 0u};
        if (sok[k]) v = *(const uint4*)(sptr[k] + (ch + 1) * 32);
        sv[k] = v;
      }
    }
    // ---- compute: 9 taps x {4 A-loads, 8x(B ds_read + 4 MFMA)} ----
#pragma unroll
    for (int tap = 0; tap < 9; ++tap) {
      const int dy = tap / 3;
      const int dx = tap - 3 * dy;
      short8 A[4];
#pragma unroll
      for (int m = 0; m < 4; ++m)
        A[m] = *(const short8*)(wtb + (((size_t)tap * COUT + co0 + 16 * m + l15) * CIN +
                                       ch * 32 + lg * 8));
#pragma unroll
      for (int n = 0; n < 8; ++n) {
        const int brow = 4 * wv + (n >> 1) + dy;
        const int bcol = 16 * (n & 1) + l15 + dx;
        const int px = brow * 34 + bcol;
        const int byt = (px >> 1) * 128 + ((lg * 16 + (px & 1) * 64) ^ (((px >> 1) & 7) << 4));
        short8 Bv = *(const short8*)((const char*)tile + byt);
        __builtin_amdgcn_s_setprio(1);
#pragma unroll
        for (int m = 0; m < 4; ++m)
          acc[m][n] = __builtin_amdgcn_mfma_f32_16x16x32_bf16(A[m], Bv, acc[m][n], 0, 0, 0);
        __builtin_amdgcn_s_setprio(0);
      }
    }
  }

  float scol[4][4];
  if (DYN) {
#pragma unroll
    for (int m = 0; m < 4; ++m)
#pragma unroll
      for (int f = 0; f < 4; ++f) scol[m][f] = 0.f;
  }

#pragma unroll
  for (int m = 0; m < 4; ++m) {
    const f32x4 bs = *(const f32x4*)(biasb + co0 + 16 * m + 4 * lg);
#pragma unroll
    for (int n = 0; n < 8; ++n) {
      f32x4 v = acc[m][n] + bs;
      if (RELU) {
        v.x = fmaxf(v.x, 0.f); v.y = fmaxf(v.y, 0.f);
        v.z = fmaxf(v.z, 0.f); v.w = fmaxf(v.w, 0.f);
      }
      const int yy = y0 + 4 * wv + (n >> 1);
      const int xx = x0 + 16 * (n & 1) + l15;
      if (!DYN) {
        uint2 pk;
        pk.x = pack2(v.x, v.y);
        pk.y = pack2(v.z, v.w);
        *(uint2*)(out_cl + (size_t)bz * HH * WW * OSTR +
                  ((size_t)(yy * WW + xx)) * OSTR + co0 + 16 * m + 4 * lg) = pk;
      } else {
        const size_t base = ((size_t)(bz * 64 + 16 * m + 4 * lg) * HH + yy) * WW + xx;
        y_out[base]             = v.x;
        y_out[base + 1 * 65536] = v.y;
        y_out[base + 2 * 65536] = v.z;
        y_out[base + 3 * 65536] = v.w;
        scol[m][0] += v.x; scol[m][1] += v.y; scol[m][2] += v.z; scol[m][3] += v.w;
      }
    }
  }
  if (DYN) {
#pragma unroll
    for (int m = 0; m < 4; ++m)
#pragma unroll
      for (int f = 0; f < 4; ++f) {
        float r = scol[m][f];
        r += __shfl_xor(r, 1, 64);
        r += __shfl_xor(r, 2, 64);
        r += __shfl_xor(r, 4, 64);
        r += __shfl_xor(r, 8, 64);
        scol[m][f] = r;
      }
    __syncthreads();  // tile dead; reuse as fp32 scratch
    float* red = (float*)tile;
    if (l15 == 0) {
#pragma unroll
      for (int m = 0; m < 4; ++m)
#pragma unroll
        for (int f = 0; f < 4; ++f)
          red[wv * 64 + 16 * m + 4 * lg + f] = scol[m][f];
    }
    __syncthreads();
    if (tid < 64) {
      const float s = red[tid] + red[64 + tid] + red[128 + tid] + red[192 + tid];
      pblk[((size_t)bz * 128 + blockIdx.y * 8 + blockIdx.x) * 64 + tid] = s;
    }
  }
}

// ---------------- SE gate: 4 blocks (one per sample) ----------------
__global__ __launch_bounds__(256) void gate_k(const float* __restrict__ pblk,
                                              const float* __restrict__ se_w1,
                                              const float* __restrict__ se_w2,
                                              float* __restrict__ gate) {
  const int b = blockIdx.x;
  const int t = threadIdx.x;
  const int c = t & 63, part = t >> 6;
  __shared__ float ps[4][64];
  __shared__ float p_s[64], h_s[16];
  float s = 0.f;
  for (int blk = part; blk < 128; blk += 4)
    s += pblk[((size_t)b * 128 + blk) * 64 + c];
  ps[part][c] = s;
  __syncthreads();
  if (t < 64) p_s[t] = (ps[0][t] + ps[1][t] + ps[2][t] + ps[3][t]) * (1.f / 65536.f);
  __syncthreads();
  if (t < 16) {
    float h = 0.f;
    for (int cc = 0; cc < 64; ++cc) h += p_s[cc] * se_w1[t * 64 + cc];
    h_s[t] = fmaxf(h, 0.f);
  }
  __syncthreads();
  if (t < 64) {
    float a = 0.f;
    for (int j = 0; j < 16; ++j) a += h_s[j] * se_w2[t * 16 + j];
    gate[b * 64 + t] = 1.f / (1.f + expf(-a));
  }
}

// ---------------- final: out = x + y*gate (in-place on d_out) ----------------
__global__ __launch_bounds__(256) void final_k(const float* __restrict__ x,
                                               const float* __restrict__ gate,
                                               float* __restrict__ out) {
  const size_t i = ((size_t)blockIdx.x * 256 + threadIdx.x) * 4;
  f32x4 yv = *(f32x4*)(out + i);
  const f32x4 xv = *(const f32x4*)(x + i);
  const float g = gate[(int)(i >> 16)];
  yv = xv + yv * g;
  *(f32x4*)(out + i) = yv;
}

// ---------------- workspace layout (batched) ----------------
static constexpr size_t SZ_XCL = (size_t)4 * 256 * 256 * 64 * 2;   // 33.55 MB
static constexpr size_t SZ_W   = (size_t)9 * 256 * 64 * 2;         // 294912
static constexpr size_t SZ_PBLK = (size_t)4 * 128 * 64 * 4;        // 131072

static constexpr size_t B_XCL = 0;                                 // also r2 (aliased)
static constexpr size_t B_R   = B_XCL + SZ_XCL;
static constexpr size_t B_W1T = B_R + 4 * SZ_XCL;                  // 134.2 MB of r
static constexpr size_t B_W2T = B_W1T + SZ_W;
static constexpr size_t B_WBT = B_W2T + SZ_W;
static constexpr size_t B_DSC = B_WBT + SZ_W;
static constexpr size_t B_BB  = B_DSC + 256;
static constexpr size_t B_GT  = B_BB + 1024;
static constexpr size_t B_PBLK = B_GT + 1024;
static constexpr size_t WS_BIG = B_PBLK + SZ_PBLK;

extern "C" void kernel_launch(void* const* d_in, const int* in_sizes, int n_in,
                              void* d_out, int out_size, void* d_ws, size_t ws_size,
                              hipStream_t stream) {
  (void)in_sizes; (void)n_in; (void)out_size;
  if (ws_size < WS_BIG) return;  // ~169 MB scratch required (harness provides it)

  const float* x     = (const float*)d_in[0];
  const float* scale = (const float*)d_in[1];
  const float* v1    = (const float*)d_in[2];
  const float* g1    = (const float*)d_in[3];
  const float* b1    = (const float*)d_in[4];
  const float* v2    = (const float*)d_in[5];
  const float* g2    = (const float*)d_in[6];
  const float* b2    = (const float*)d_in[7];
  const float* dyn_v = (const float*)d_in[8];
  const float* dyn_g = (const float*)d_in[9];
  const float* dyn_b = (const float*)d_in[10];
  const float* att_w = (const float*)d_in[11];
  const float* att_b = (const float*)d_in[12];
  const float* se_w1 = (const float*)d_in[13];
  const float* se_w2 = (const float*)d_in[14];
  float* out = (float*)d_out;

  char* ws = (char*)d_ws;
  unsigned short* xcl  = (unsigned short*)(ws + B_XCL);
  unsigned short* rbuf = (unsigned short*)(ws + B_R);
  unsigned short* r2   = (unsigned short*)(ws + B_XCL);  // aliases dead xcl
  unsigned short* w1t  = (unsigned short*)(ws + B_W1T);
  unsigned short* w2t  = (unsigned short*)(ws + B_W2T);
  unsigned short* wbt  = (unsigned short*)(ws + B_WBT);
  float* dscale = (float*)(ws + B_DSC);
  float* bias_b = (float*)(ws + B_BB);
  float* gate   = (float*)(ws + B_GT);
  float* pblk   = (float*)(ws + B_PBLK);

  xpose_k<<<dim3(4, 256, 4), 256, 0, stream>>>(x, xcl);
  wnorm_k<256, 64><<<256, 256, 0, stream>>>(v1, g1, w1t);
  wnorm_k<64, 256><<<64, 256, 0, stream>>>(v2, g2, w2t);
  dynnorm_k<<<4, 256, 0, stream>>>(dyn_v, dyn_g, dscale);
  mix_k<<<256, 256, 0, stream>>>(scale, att_w, att_b, dyn_v, dyn_b, dscale, wbt, bias_b);

  conv3x3_mfma<64, 256, 256, true, false><<<dim3(8, 16, 16), 256, 0, stream>>>(
      xcl, w1t, b1, rbuf, nullptr, nullptr);
  conv3x3_mfma<256, 64, 64, false, false><<<dim3(8, 16, 4), 256, 0, stream>>>(
      rbuf, w2t, b2, r2, nullptr, nullptr);
  conv3x3_mfma<64, 64, 64, false, true><<<dim3(8, 16, 4), 256, 0, stream>>>(
      r2, wbt, bias_b, nullptr, out, pblk);

  gate_k<<<4, 256, 0, stream>>>(pblk, se_w1, se_w2, gate);
  final_k<<<16384, 256, 0, stream>>>(x, gate, out);
}

// Round 5
// 496.348 us; speedup vs baseline: 1.3294x; 1.0300x over previous
//
#include <hip/hip_runtime.h>

typedef __attribute__((ext_vector_type(8))) short short8;
typedef __attribute__((ext_vector_type(4))) float f32x4;

#define HH 256
#define WW 256

__device__ inline unsigned int f2bf(float x) {
  unsigned int u = __float_as_uint(x);
  return (u + 0x7fffu + ((u >> 16) & 1u)) >> 16;   // RTNE truncation to bf16
}
__device__ inline unsigned int pack2(float a, float b) {
  return f2bf(a) | (f2bf(b) << 16);
}

// ---------------- transpose x (fp32 NCHW) -> xcl bf16 [B][H][W][64] ----------------
__global__ __launch_bounds__(256) void xpose_k(const float* __restrict__ x,
                                               unsigned short* __restrict__ xcl) {
  const int t = threadIdx.x;
  const int ci = t & 63;
  const int wv = t >> 6;
  const int x0 = blockIdx.x * 64;
  const int y  = blockIdx.y;
  const int b  = blockIdx.z;
  const float* src = x + ((size_t)(b * 64 + ci) * HH + y) * WW + x0 + wv;
  unsigned short* dst = xcl + ((size_t)(b * HH + y) * WW + x0 + wv) * 64 + ci;
#pragma unroll
  for (int k = 0; k < 16; ++k)
    dst[(size_t)k * 4 * 64] = (unsigned short)f2bf(src[4 * k]);
}

// ---------------- weight norm -> [tap][co][ci] bf16 ----------------
template <int COUT, int CINK>
__global__ __launch_bounds__(256) void wnorm_k(const float* __restrict__ v,
                                               const float* __restrict__ g,
                                               unsigned short* __restrict__ out) {
  constexpr int N = CINK * 9;
  const int co = blockIdx.x, t = threadIdx.x;
  const float* vb = v + (size_t)co * N;
  float s = 0.f;
  for (int i = t; i < N; i += 256) { float a = vb[i]; s += a * a; }
  for (int off = 32; off > 0; off >>= 1) s += __shfl_xor(s, off, 64);
  __shared__ float red[4];
  if ((t & 63) == 0) red[t >> 6] = s;
  __syncthreads();
  const float tot = red[0] + red[1] + red[2] + red[3];
  const float sc = g[co] / sqrtf(tot);
  for (int i = t; i < N; i += 256) {
    int ci = i / 9, tap = i - 9 * (i / 9);
    out[((size_t)tap * COUT + co) * CINK + ci] = (unsigned short)f2bf(vb[i] * sc);
  }
}

// ---------------- dyn bank norms ----------------
__global__ __launch_bounds__(256) void dynnorm_k(const float* __restrict__ dyn_v,
                                                 const float* __restrict__ dyn_g,
                                                 float* __restrict__ dscale) {
  const int k = blockIdx.x, t = threadIdx.x;
  const float* vb = dyn_v + (size_t)k * 36864;
  float s = 0.f;
  for (int i = t; i < 36864; i += 256) { float a = vb[i]; s += a * a; }
  for (int off = 32; off > 0; off >>= 1) s += __shfl_xor(s, off, 64);
  __shared__ float red[4];
  if ((t & 63) == 0) red[t >> 6] = s;
  __syncthreads();
  if (t == 0) dscale[k] = dyn_g[k] / sqrtf(red[0] + red[1] + red[2] + red[3]);
}

// ---------------- per-sample mixed dyn weights + bias ----------------
__global__ __launch_bounds__(256) void mix_k(const float* __restrict__ scale,
                                             const float* __restrict__ att_w,
                                             const float* __restrict__ att_b,
                                             const float* __restrict__ dyn_v,
                                             const float* __restrict__ dyn_b,
                                             const float* __restrict__ dscale,
                                             unsigned short* __restrict__ wbt,
                                             float* __restrict__ bias_b) {
  const int blk = blockIdx.x;
  const int b = blk >> 6, co = blk & 63;
  const int t = threadIdx.x;
  float att[4], wsc[4];
  const float sc = scale[b];
  float mx = -1e30f;
#pragma unroll
  for (int k = 0; k < 4; ++k) { att[k] = sc * att_w[k] + att_b[k]; mx = fmaxf(mx, att[k]); }
  float den = 0.f;
#pragma unroll
  for (int k = 0; k < 4; ++k) { att[k] = expf(att[k] - mx); den += att[k]; }
#pragma unroll
  for (int k = 0; k < 4; ++k) { att[k] /= den; wsc[k] = att[k] * dscale[k]; }
  for (int i = t; i < 576; i += 256) {
    int ci = i / 9, tap = i - 9 * (i / 9);
    float w = 0.f;
#pragma unroll
    for (int k = 0; k < 4; ++k)
      w += wsc[k] * dyn_v[(((size_t)k * 64 + co) * 64 + ci) * 9 + tap];
    wbt[(((size_t)b * 9 + tap) * 64 + co) * 64 + ci] = (unsigned short)f2bf(w);
  }
  if (t == 0) {
    float bb = 0.f;
#pragma unroll
    for (int k = 0; k < 4; ++k) bb += att[k] * dyn_b[k * 64 + co];
    bias_b[blk] = bb;
  }
}

// ---------------- MFMA 3x3 conv v5: v4 + XCD-aware block swizzle (T1) ----------------
// 1-D grid, nwg = NBZ*16*8*CO_TILES (divisible by 8). Block id remap:
//   wg = (bid & 7) * (nwg/8) + (bid >> 3)
// so each XCD owns a contiguous slab; within the slab cot is fastest (co-tiles of the
// same pixel tile run back-to-back -> halo L2-resident), then x, then y, then bz.
// Block: 64co x 16rows x 32cols; wave = m4(64co) x n8(4r x 2colhalf); ci-chunk 32.
// LDS halo tile 18x34x32ci bf16 = 39168 B, 128B-pair-row swizzle:
//   byte(px,lg) = (px>>1)*128 + ((lg*16 + (px&1)*64) ^ (((px>>1)&7)<<4))
template <int CIN, int COUT, int OSTR, bool RELU, bool DYN>
__global__ __launch_bounds__(256, 2) void conv3x3_mfma(const unsigned short* __restrict__ in_cl,
                                                       const unsigned short* __restrict__ wt,
                                                       const float* __restrict__ bias,
                                                       unsigned short* __restrict__ out_cl,
                                                       float* __restrict__ y_out,
                                                       float* __restrict__ pblk) {
  constexpr int CO_TILES = COUT / 64;
  constexpr int NCH = CIN / 32;
  constexpr int NSLOT = 612 * 4;  // 18*34 px * 4 lg-groups
  const int tid = threadIdx.x;
  const int lane = tid & 63;
  const int wv = tid >> 6;
  const int l15 = lane & 15;
  const int lg = lane >> 4;

  // ---- XCD-aware swizzle (bijective: gridDim.x % 8 == 0) ----
  const int wg = (blockIdx.x & 7) * (gridDim.x >> 3) + (blockIdx.x >> 3);
  int tdec = wg;
  const int cot = tdec % CO_TILES; tdec /= CO_TILES;
  const int bx = tdec & 7; tdec >>= 3;
  const int by = tdec & 15; tdec >>= 4;
  const int bz = tdec;

  const int x0 = bx * 32;
  const int y0 = by * 16;
  const int co0 = cot * 64;

  const unsigned short* inb = in_cl + (size_t)bz * HH * WW * CIN;
  const unsigned short* wtb = wt + (DYN ? (size_t)bz * 9 * 64 * 64 : (size_t)0);
  const float* biasb = bias + (DYN ? bz * 64 : 0);

  __shared__ unsigned short tile[NSLOT * 8];  // 39168 B

  // ---- precompute per-thread staging slots ----
  const unsigned short* sptr[10];
  int sbyte[10];
  bool sok[10], sw[10];
#pragma unroll
  for (int k = 0; k < 10; ++k) {
    const int u = k * 256 + tid;
    const int px = u >> 2, g = u & 3;
    const int row = px / 34, col = px - 34 * row;
    const int gy = y0 - 1 + row, gx = x0 - 1 + col;
    sw[k] = (u < NSLOT);
    sok[k] = sw[k] && ((unsigned)gy < (unsigned)HH) && ((unsigned)gx < (unsigned)WW);
    sptr[k] = inb + (sok[k] ? ((size_t)(gy * WW + gx)) * CIN + g * 8 : (size_t)0);
    sbyte[k] = (px >> 1) * 128 + ((g * 16 + (px & 1) * 64) ^ (((px >> 1) & 7) << 4));
  }

  f32x4 acc[4][8];
#pragma unroll
  for (int m = 0; m < 4; ++m)
#pragma unroll
    for (int n = 0; n < 8; ++n) acc[m][n] = (f32x4){0.f, 0.f, 0.f, 0.f};

  // preload chunk 0
  uint4 sv[10];
#pragma unroll
  for (int k = 0; k < 10; ++k) {
    uint4 v = {0u, 0u, 0u, 0u};
    if (sok[k]) v = *(const uint4*)(sptr[k]);
    sv[k] = v;
  }

#pragma unroll 1
  for (int ch = 0; ch < NCH; ++ch) {
    if (ch) __syncthreads();  // previous chunk's compute done before overwrite
#pragma unroll
    for (int k = 0; k < 10; ++k)
      if (sw[k]) *(uint4*)((char*)tile + sbyte[k]) = sv[k];
    __syncthreads();
    if (ch + 1 < NCH) {  // issue next chunk's loads early (T14)
#pragma unroll
      for (int k = 0; k < 10; ++k) {
        uint4 v = {0u, 0u, 0u, 0u};
        if (sok[k]) v = *(const uint4*)(sptr[k] + (ch + 1) * 32);
        sv[k] = v;
      }
    }
    // ---- compute: 9 taps x {4 A-loads, 8x(B ds_read + 4 MFMA)} ----
#pragma unroll
    for (int tap = 0; tap < 9; ++tap) {
      const int dy = tap / 3;
      const int dx = tap - 3 * dy;
      short8 A[4];
#pragma unroll
      for (int m = 0; m < 4; ++m)
        A[m] = *(const short8*)(wtb + (((size_t)tap * COUT + co0 + 16 * m + l15) * CIN +
                                       ch * 32 + lg * 8));
#pragma unroll
      for (int n = 0; n < 8; ++n) {
        const int brow = 4 * wv + (n >> 1) + dy;
        const int bcol = 16 * (n & 1) + l15 + dx;
        const int px = brow * 34 + bcol;
        const int byt = (px >> 1) * 128 + ((lg * 16 + (px & 1) * 64) ^ (((px >> 1) & 7) << 4));
        short8 Bv = *(const short8*)((const char*)tile + byt);
        __builtin_amdgcn_s_setprio(1);
#pragma unroll
        for (int m = 0; m < 4; ++m)
          acc[m][n] = __builtin_amdgcn_mfma_f32_16x16x32_bf16(A[m], Bv, acc[m][n], 0, 0, 0);
        __builtin_amdgcn_s_setprio(0);
      }
    }
  }

  float scol[4][4];
  if (DYN) {
#pragma unroll
    for (int m = 0; m < 4; ++m)
#pragma unroll
      for (int f = 0; f < 4; ++f) scol[m][f] = 0.f;
  }

#pragma unroll
  for (int m = 0; m < 4; ++m) {
    const f32x4 bs = *(const f32x4*)(biasb + co0 + 16 * m + 4 * lg);
#pragma unroll
    for (int n = 0; n < 8; ++n) {
      f32x4 v = acc[m][n] + bs;
      if (RELU) {
        v.x = fmaxf(v.x, 0.f); v.y = fmaxf(v.y, 0.f);
        v.z = fmaxf(v.z, 0.f); v.w = fmaxf(v.w, 0.f);
      }
      const int yy = y0 + 4 * wv + (n >> 1);
      const int xx = x0 + 16 * (n & 1) + l15;
      if (!DYN) {
        uint2 pk;
        pk.x = pack2(v.x, v.y);
        pk.y = pack2(v.z, v.w);
        *(uint2*)(out_cl + (size_t)bz * HH * WW * OSTR +
                  ((size_t)(yy * WW + xx)) * OSTR + co0 + 16 * m + 4 * lg) = pk;
      } else {
        const size_t base = ((size_t)(bz * 64 + 16 * m + 4 * lg) * HH + yy) * WW + xx;
        y_out[base]             = v.x;
        y_out[base + 1 * 65536] = v.y;
        y_out[base + 2 * 65536] = v.z;
        y_out[base + 3 * 65536] = v.w;
        scol[m][0] += v.x; scol[m][1] += v.y; scol[m][2] += v.z; scol[m][3] += v.w;
      }
    }
  }
  if (DYN) {
#pragma unroll
    for (int m = 0; m < 4; ++m)
#pragma unroll
      for (int f = 0; f < 4; ++f) {
        float r = scol[m][f];
        r += __shfl_xor(r, 1, 64);
        r += __shfl_xor(r, 2, 64);
        r += __shfl_xor(r, 4, 64);
        r += __shfl_xor(r, 8, 64);
        scol[m][f] = r;
      }
    __syncthreads();  // tile dead; reuse as fp32 scratch
    float* red = (float*)tile;
    if (l15 == 0) {
#pragma unroll
      for (int m = 0; m < 4; ++m)
#pragma unroll
        for (int f = 0; f < 4; ++f)
          red[wv * 64 + 16 * m + 4 * lg + f] = scol[m][f];
    }
    __syncthreads();
    if (tid < 64) {
      const float s = red[tid] + red[64 + tid] + red[128 + tid] + red[192 + tid];
      pblk[((size_t)bz * 128 + by * 8 + bx) * 64 + tid] = s;
    }
  }
}

// ---------------- SE gate: 4 blocks (one per sample) ----------------
__global__ __launch_bounds__(256) void gate_k(const float* __restrict__ pblk,
                                              const float* __restrict__ se_w1,
                                              const float* __restrict__ se_w2,
                                              float* __restrict__ gate) {
  const int b = blockIdx.x;
  const int t = threadIdx.x;
  const int c = t & 63, part = t >> 6;
  __shared__ float ps[4][64];
  __shared__ float p_s[64], h_s[16];
  float s = 0.f;
  for (int blk = part; blk < 128; blk += 4)
    s += pblk[((size_t)b * 128 + blk) * 64 + c];
  ps[part][c] = s;
  __syncthreads();
  if (t < 64) p_s[t] = (ps[0][t] + ps[1][t] + ps[2][t] + ps[3][t]) * (1.f / 65536.f);
  __syncthreads();
  if (t < 16) {
    float h = 0.f;
    for (int cc = 0; cc < 64; ++cc) h += p_s[cc] * se_w1[t * 64 + cc];
    h_s[t] = fmaxf(h, 0.f);
  }
  __syncthreads();
  if (t < 64) {
    float a = 0.f;
    for (int j = 0; j < 16; ++j) a += h_s[j] * se_w2[t * 16 + j];
    gate[b * 64 + t] = 1.f / (1.f + expf(-a));
  }
}

// ---------------- final: out = x + y*gate (in-place on d_out) ----------------
__global__ __launch_bounds__(256) void final_k(const float* __restrict__ x,
                                               const float* __restrict__ gate,
                                               float* __restrict__ out) {
  const size_t i = ((size_t)blockIdx.x * 256 + threadIdx.x) * 4;
  f32x4 yv = *(f32x4*)(out + i);
  const f32x4 xv = *(const f32x4*)(x + i);
  const float g = gate[(int)(i >> 16)];
  yv = xv + yv * g;
  *(f32x4*)(out + i) = yv;
}

// ---------------- workspace layout (batched) ----------------
static constexpr size_t SZ_XCL = (size_t)4 * 256 * 256 * 64 * 2;   // 33.55 MB
static constexpr size_t SZ_W   = (size_t)9 * 256 * 64 * 2;         // 294912
static constexpr size_t SZ_PBLK = (size_t)4 * 128 * 64 * 4;        // 131072

static constexpr size_t B_XCL = 0;                                 // also r2 (aliased)
static constexpr size_t B_R   = B_XCL + SZ_XCL;
static constexpr size_t B_W1T = B_R + 4 * SZ_XCL;                  // 134.2 MB of r
static constexpr size_t B_W2T = B_W1T + SZ_W;
static constexpr size_t B_WBT = B_W2T + SZ_W;
static constexpr size_t B_DSC = B_WBT + SZ_W;
static constexpr size_t B_BB  = B_DSC + 256;
static constexpr size_t B_GT  = B_BB + 1024;
static constexpr size_t B_PBLK = B_GT + 1024;
static constexpr size_t WS_BIG = B_PBLK + SZ_PBLK;

extern "C" void kernel_launch(void* const* d_in, const int* in_sizes, int n_in,
                              void* d_out, int out_size, void* d_ws, size_t ws_size,
                              hipStream_t stream) {
  (void)in_sizes; (void)n_in; (void)out_size;
  if (ws_size < WS_BIG) return;  // ~169 MB scratch required (harness provides it)

  const float* x     = (const float*)d_in[0];
  const float* scale = (const float*)d_in[1];
  const float* v1    = (const float*)d_in[2];
  const float* g1    = (const float*)d_in[3];
  const float* b1    = (const float*)d_in[4];
  const float* v2    = (const float*)d_in[5];
  const float* g2    = (const float*)d_in[6];
  const float* b2    = (const float*)d_in[7];
  const float* dyn_v = (const float*)d_in[8];
  const float* dyn_g = (const float*)d_in[9];
  const float* dyn_b = (const float*)d_in[10];
  const float* att_w = (const float*)d_in[11];
  const float* att_b = (const float*)d_in[12];
  const float* se_w1 = (const float*)d_in[13];
  const float* se_w2 = (const float*)d_in[14];
  float* out = (float*)d_out;

  char* ws = (char*)d_ws;
  unsigned short* xcl  = (unsigned short*)(ws + B_XCL);
  unsigned short* rbuf = (unsigned short*)(ws + B_R);
  unsigned short* r2   = (unsigned short*)(ws + B_XCL);  // aliases dead xcl
  unsigned short* w1t  = (unsigned short*)(ws + B_W1T);
  unsigned short* w2t  = (unsigned short*)(ws + B_W2T);
  unsigned short* wbt  = (unsigned short*)(ws + B_WBT);
  float* dscale = (float*)(ws + B_DSC);
  float* bias_b = (float*)(ws + B_BB);
  float* gate   = (float*)(ws + B_GT);
  float* pblk   = (float*)(ws + B_PBLK);

  xpose_k<<<dim3(4, 256, 4), 256, 0, stream>>>(x, xcl);
  wnorm_k<256, 64><<<256, 256, 0, stream>>>(v1, g1, w1t);
  wnorm_k<64, 256><<<64, 256, 0, stream>>>(v2, g2, w2t);
  dynnorm_k<<<4, 256, 0, stream>>>(dyn_v, dyn_g, dscale);
  mix_k<<<256, 256, 0, stream>>>(scale, att_w, att_b, dyn_v, dyn_b, dscale, wbt, bias_b);

  // 1-D grids, all divisible by 8 (bijective XCD swizzle)
  conv3x3_mfma<64, 256, 256, true, false><<<2048, 256, 0, stream>>>(
      xcl, w1t, b1, rbuf, nullptr, nullptr);
  conv3x3_mfma<256, 64, 64, false, false><<<512, 256, 0, stream>>>(
      rbuf, w2t, b2, r2, nullptr, nullptr);
  conv3x3_mfma<64, 64, 64, false, true><<<512, 256, 0, stream>>>(
      r2, wbt, bias_b, nullptr, out, pblk);

  gate_k<<<4, 256, 0, stream>>>(pblk, se_w1, se_w2, gate);
  final_k<<<16384, 256, 0, stream>>>(x, gate, out);
}

// Round 6
// 432.867 us; speedup vs baseline: 1.5244x; 1.1467x over previous
//
#include <hip/hip_runtime.h>

typedef __attribute__((ext_vector_type(8))) short short8;
typedef __attribute__((ext_vector_type(4))) float f32x4;

#define HH 256
#define WW 256

__device__ inline unsigned int f2bf(float x) {
  unsigned int u = __float_as_uint(x);
  return (u + 0x7fffu + ((u >> 16) & 1u)) >> 16;   // RTNE truncation to bf16
}
__device__ inline unsigned int pack2(float a, float b) {
  return f2bf(a) | (f2bf(b) << 16);
}

// ---------------- transpose x (fp32 NCHW) -> xcl bf16 [B][H][W][64] ----------------
__global__ __launch_bounds__(256) void xpose_k(const float* __restrict__ x,
                                               unsigned short* __restrict__ xcl) {
  const int t = threadIdx.x;
  const int ci = t & 63;
  const int wv = t >> 6;
  const int x0 = blockIdx.x * 64;
  const int y  = blockIdx.y;
  const int b  = blockIdx.z;
  const float* src = x + ((size_t)(b * 64 + ci) * HH + y) * WW + x0 + wv;
  unsigned short* dst = xcl + ((size_t)(b * HH + y) * WW + x0 + wv) * 64 + ci;
#pragma unroll
  for (int k = 0; k < 16; ++k)
    dst[(size_t)k * 4 * 64] = (unsigned short)f2bf(src[4 * k]);
}

// ---------------- weight norm -> [tap][co][ci] bf16 ----------------
template <int COUT, int CINK>
__global__ __launch_bounds__(256) void wnorm_k(const float* __restrict__ v,
                                               const float* __restrict__ g,
                                               unsigned short* __restrict__ out) {
  constexpr int N = CINK * 9;
  const int co = blockIdx.x, t = threadIdx.x;
  const float* vb = v + (size_t)co * N;
  float s = 0.f;
  for (int i = t; i < N; i += 256) { float a = vb[i]; s += a * a; }
  for (int off = 32; off > 0; off >>= 1) s += __shfl_xor(s, off, 64);
  __shared__ float red[4];
  if ((t & 63) == 0) red[t >> 6] = s;
  __syncthreads();
  const float tot = red[0] + red[1] + red[2] + red[3];
  const float sc = g[co] / sqrtf(tot);
  for (int i = t; i < N; i += 256) {
    int ci = i / 9, tap = i - 9 * (i / 9);
    out[((size_t)tap * COUT + co) * CINK + ci] = (unsigned short)f2bf(vb[i] * sc);
  }
}

// ---------------- dyn bank norms ----------------
__global__ __launch_bounds__(256) void dynnorm_k(const float* __restrict__ dyn_v,
                                                 const float* __restrict__ dyn_g,
                                                 float* __restrict__ dscale) {
  const int k = blockIdx.x, t = threadIdx.x;
  const float* vb = dyn_v + (size_t)k * 36864;
  float s = 0.f;
  for (int i = t; i < 36864; i += 256) { float a = vb[i]; s += a * a; }
  for (int off = 32; off > 0; off >>= 1) s += __shfl_xor(s, off, 64);
  __shared__ float red[4];
  if ((t & 63) == 0) red[t >> 6] = s;
  __syncthreads();
  if (t == 0) dscale[k] = dyn_g[k] / sqrtf(red[0] + red[1] + red[2] + red[3]);
}

// ---------------- per-sample mixed dyn weights + bias ----------------
__global__ __launch_bounds__(256) void mix_k(const float* __restrict__ scale,
                                             const float* __restrict__ att_w,
                                             const float* __restrict__ att_b,
                                             const float* __restrict__ dyn_v,
                                             const float* __restrict__ dyn_b,
                                             const float* __restrict__ dscale,
                                             unsigned short* __restrict__ wbt,
                                             float* __restrict__ bias_b) {
  const int blk = blockIdx.x;
  const int b = blk >> 6, co = blk & 63;
  const int t = threadIdx.x;
  float att[4], wsc[4];
  const float sc = scale[b];
  float mx = -1e30f;
#pragma unroll
  for (int k = 0; k < 4; ++k) { att[k] = sc * att_w[k] + att_b[k]; mx = fmaxf(mx, att[k]); }
  float den = 0.f;
#pragma unroll
  for (int k = 0; k < 4; ++k) { att[k] = expf(att[k] - mx); den += att[k]; }
#pragma unroll
  for (int k = 0; k < 4; ++k) { att[k] /= den; wsc[k] = att[k] * dscale[k]; }
  for (int i = t; i < 576; i += 256) {
    int ci = i / 9, tap = i - 9 * (i / 9);
    float w = 0.f;
#pragma unroll
    for (int k = 0; k < 4; ++k)
      w += wsc[k] * dyn_v[(((size_t)k * 64 + co) * 64 + ci) * 9 + tap];
    wbt[(((size_t)b * 9 + tap) * 64 + co) * 64 + ci] = (unsigned short)f2bf(w);
  }
  if (t == 0) {
    float bb = 0.f;
#pragma unroll
    for (int k = 0; k < 4; ++k) bb += att[k] * dyn_b[k * 64 + co];
    bias_b[blk] = bb;
  }
}

// ---------------- MFMA 3x3 conv v6: A-panel in LDS ----------------
// Block: 64co x 16rows x 32cols; wave = m4(64co) x n8(4r x 2colhalf); ci-chunk 32.
// Input halo tile 18x34x32ci bf16 = 39168 B, 128B-pair-row swizzle:
//   byte(px,lg) = (px>>1)*128 + ((lg*16 + (px&1)*64) ^ (((px>>1)&7)<<4))
// A panel per chunk: [tap][g][co] bf16, byte = (tap*4+g)*1024 + co*16 (36864 B).
// Both A staging writes and A tap-reads are structurally bank-balanced (8 words/bank).
// XCD swizzle: 1-D grid, wg = (bid&7)*(nwg/8) + (bid>>3), cot fastest.
template <int CIN, int COUT, int OSTR, bool RELU, bool DYN>
__global__ __launch_bounds__(256, 2) void conv3x3_mfma(const unsigned short* __restrict__ in_cl,
                                                       const unsigned short* __restrict__ wt,
                                                       const float* __restrict__ bias,
                                                       unsigned short* __restrict__ out_cl,
                                                       float* __restrict__ y_out,
                                                       float* __restrict__ pblk) {
  constexpr int CO_TILES = COUT / 64;
  constexpr int NCH = CIN / 32;
  constexpr int NSLOT = 612 * 4;  // 18*34 px * 4 lg-groups
  const int tid = threadIdx.x;
  const int lane = tid & 63;
  const int wv = tid >> 6;
  const int l15 = lane & 15;
  const int lg = lane >> 4;

  // ---- XCD-aware swizzle (bijective: gridDim.x % 8 == 0) ----
  const int wg = (blockIdx.x & 7) * (gridDim.x >> 3) + (blockIdx.x >> 3);
  int tdec = wg;
  const int cot = tdec % CO_TILES; tdec /= CO_TILES;
  const int bx = tdec & 7; tdec >>= 3;
  const int by = tdec & 15; tdec >>= 4;
  const int bz = tdec;

  const int x0 = bx * 32;
  const int y0 = by * 16;
  const int co0 = cot * 64;

  const unsigned short* inb = in_cl + (size_t)bz * HH * WW * CIN;
  const unsigned short* wtb = wt + (DYN ? (size_t)bz * 9 * 64 * 64 : (size_t)0);
  const float* biasb = bias + (DYN ? bz * 64 : 0);

  __shared__ unsigned short tile[NSLOT * 8];   // 39168 B input halo
  __shared__ unsigned short atile[9 * 4 * 64 * 8];  // 36864 B A panel

  // ---- precompute per-thread input staging slots ----
  const unsigned short* sptr[10];
  int sbyte[10];
  bool sok[10], sw[10];
#pragma unroll
  for (int k = 0; k < 10; ++k) {
    const int u = k * 256 + tid;
    const int px = u >> 2, g = u & 3;
    const int row = px / 34, col = px - 34 * row;
    const int gy = y0 - 1 + row, gx = x0 - 1 + col;
    sw[k] = (u < NSLOT);
    sok[k] = sw[k] && ((unsigned)gy < (unsigned)HH) && ((unsigned)gx < (unsigned)WW);
    sptr[k] = inb + (sok[k] ? ((size_t)(gy * WW + gx)) * CIN + g * 8 : (size_t)0);
    sbyte[k] = (px >> 1) * 128 + ((g * 16 + (px & 1) * 64) ^ (((px >> 1) & 7) << 4));
  }
  // ---- per-thread A staging slot (9 iters x 256 threads = full panel) ----
  const int a_tap = 0;  // computed per-k below

  f32x4 acc[4][8];
#pragma unroll
  for (int m = 0; m < 4; ++m)
#pragma unroll
    for (int n = 0; n < 8; ++n) acc[m][n] = (f32x4){0.f, 0.f, 0.f, 0.f};

  // preload input chunk 0
  uint4 sv[10];
#pragma unroll
  for (int k = 0; k < 10; ++k) {
    uint4 v = {0u, 0u, 0u, 0u};
    if (sok[k]) v = *(const uint4*)(sptr[k]);
    sv[k] = v;
  }
  (void)a_tap;

#pragma unroll 1
  for (int ch = 0; ch < NCH; ++ch) {
    if (ch) __syncthreads();  // previous chunk's compute done before overwrite
    // (1) input sv -> tile (sv regs die here)
#pragma unroll
    for (int k = 0; k < 10; ++k)
      if (sw[k]) *(uint4*)((char*)tile + sbyte[k]) = sv[k];
    // (2) A panel: cooperative load -> atile (transient regs, batched loads)
    {
      uint4 aw[9];
#pragma unroll
      for (int k = 0; k < 9; ++k) {
        const int idx = k * 256 + tid;
        const int tap = idx >> 8;
        const int co = (idx >> 2) & 63;
        const int g = idx & 3;
        aw[k] = *(const uint4*)(wtb + ((size_t)(tap * COUT + co0 + co) * CIN + ch * 32 + g * 8));
      }
#pragma unroll
      for (int k = 0; k < 9; ++k) {
        const int idx = k * 256 + tid;
        const int tap = idx >> 8;
        const int co = (idx >> 2) & 63;
        const int g = idx & 3;
        *(uint4*)((char*)atile + ((tap * 4 + g) * 1024 + co * 16)) = aw[k];
      }
    }
    __syncthreads();
    // (3) prefetch next input chunk into sv (T14)
    if (ch + 1 < NCH) {
#pragma unroll
      for (int k = 0; k < 10; ++k) {
        uint4 v = {0u, 0u, 0u, 0u};
        if (sok[k]) v = *(const uint4*)(sptr[k] + (ch + 1) * 32);
        sv[k] = v;
      }
    }
    // (4) compute: 9 taps x {4 A ds_reads, 8x(B ds_read + 4 MFMA)}
#pragma unroll
    for (int tap = 0; tap < 9; ++tap) {
      const int dy = tap / 3;
      const int dx = tap - 3 * dy;
      short8 A[4];
#pragma unroll
      for (int m = 0; m < 4; ++m)
        A[m] = *(const short8*)((const char*)atile +
                                ((tap * 4 + lg) * 1024 + (16 * m + l15) * 16));
#pragma unroll
      for (int n = 0; n < 8; ++n) {
        const int brow = 4 * wv + (n >> 1) + dy;
        const int bcol = 16 * (n & 1) + l15 + dx;
        const int px = brow * 34 + bcol;
        const int byt = (px >> 1) * 128 + ((lg * 16 + (px & 1) * 64) ^ (((px >> 1) & 7) << 4));
        short8 Bv = *(const short8*)((const char*)tile + byt);
        __builtin_amdgcn_s_setprio(1);
#pragma unroll
        for (int m = 0; m < 4; ++m)
          acc[m][n] = __builtin_amdgcn_mfma_f32_16x16x32_bf16(A[m], Bv, acc[m][n], 0, 0, 0);
        __builtin_amdgcn_s_setprio(0);
      }
    }
  }

  float scol[4][4];
  if (DYN) {
#pragma unroll
    for (int m = 0; m < 4; ++m)
#pragma unroll
      for (int f = 0; f < 4; ++f) scol[m][f] = 0.f;
  }

#pragma unroll
  for (int m = 0; m < 4; ++m) {
    const f32x4 bs = *(const f32x4*)(biasb + co0 + 16 * m + 4 * lg);
#pragma unroll
    for (int n = 0; n < 8; ++n) {
      f32x4 v = acc[m][n] + bs;
      if (RELU) {
        v.x = fmaxf(v.x, 0.f); v.y = fmaxf(v.y, 0.f);
        v.z = fmaxf(v.z, 0.f); v.w = fmaxf(v.w, 0.f);
      }
      const int yy = y0 + 4 * wv + (n >> 1);
      const int xx = x0 + 16 * (n & 1) + l15;
      if (!DYN) {
        uint2 pk;
        pk.x = pack2(v.x, v.y);
        pk.y = pack2(v.z, v.w);
        *(uint2*)(out_cl + (size_t)bz * HH * WW * OSTR +
                  ((size_t)(yy * WW + xx)) * OSTR + co0 + 16 * m + 4 * lg) = pk;
      } else {
        const size_t base = ((size_t)(bz * 64 + 16 * m + 4 * lg) * HH + yy) * WW + xx;
        y_out[base]             = v.x;
        y_out[base + 1 * 65536] = v.y;
        y_out[base + 2 * 65536] = v.z;
        y_out[base + 3 * 65536] = v.w;
        scol[m][0] += v.x; scol[m][1] += v.y; scol[m][2] += v.z; scol[m][3] += v.w;
      }
    }
  }
  if (DYN) {
#pragma unroll
    for (int m = 0; m < 4; ++m)
#pragma unroll
      for (int f = 0; f < 4; ++f) {
        float r = scol[m][f];
        r += __shfl_xor(r, 1, 64);
        r += __shfl_xor(r, 2, 64);
        r += __shfl_xor(r, 4, 64);
        r += __shfl_xor(r, 8, 64);
        scol[m][f] = r;
      }
    __syncthreads();  // tile dead; reuse as fp32 scratch
    float* red = (float*)tile;
    if (l15 == 0) {
#pragma unroll
      for (int m = 0; m < 4; ++m)
#pragma unroll
        for (int f = 0; f < 4; ++f)
          red[wv * 64 + 16 * m + 4 * lg + f] = scol[m][f];
    }
    __syncthreads();
    if (tid < 64) {
      const float s = red[tid] + red[64 + tid] + red[128 + tid] + red[192 + tid];
      pblk[((size_t)bz * 128 + by * 8 + bx) * 64 + tid] = s;
    }
  }
}

// ---------------- SE gate: 4 blocks (one per sample) ----------------
__global__ __launch_bounds__(256) void gate_k(const float* __restrict__ pblk,
                                              const float* __restrict__ se_w1,
                                              const float* __restrict__ se_w2,
                                              float* __restrict__ gate) {
  const int b = blockIdx.x;
  const int t = threadIdx.x;
  const int c = t & 63, part = t >> 6;
  __shared__ float ps[4][64];
  __shared__ float p_s[64], h_s[16];
  float s = 0.f;
  for (int blk = part; blk < 128; blk += 4)
    s += pblk[((size_t)b * 128 + blk) * 64 + c];
  ps[part][c] = s;
  __syncthreads();
  if (t < 64) p_s[t] = (ps[0][t] + ps[1][t] + ps[2][t] + ps[3][t]) * (1.f / 65536.f);
  __syncthreads();
  if (t < 16) {
    float h = 0.f;
    for (int cc = 0; cc < 64; ++cc) h += p_s[cc] * se_w1[t * 64 + cc];
    h_s[t] = fmaxf(h, 0.f);
  }
  __syncthreads();
  if (t < 64) {
    float a = 0.f;
    for (int j = 0; j < 16; ++j) a += h_s[j] * se_w2[t * 16 + j];
    gate[b * 64 + t] = 1.f / (1.f + expf(-a));
  }
}

// ---------------- final: out = x + y*gate (in-place on d_out) ----------------
__global__ __launch_bounds__(256) void final_k(const float* __restrict__ x,
                                               const float* __restrict__ gate,
                                               float* __restrict__ out) {
  const size_t i = ((size_t)blockIdx.x * 256 + threadIdx.x) * 4;
  f32x4 yv = *(f32x4*)(out + i);
  const f32x4 xv = *(const f32x4*)(x + i);
  const float g = gate[(int)(i >> 16)];
  yv = xv + yv * g;
  *(f32x4*)(out + i) = yv;
}

// ---------------- workspace layout (batched) ----------------
static constexpr size_t SZ_XCL = (size_t)4 * 256 * 256 * 64 * 2;   // 33.55 MB
static constexpr size_t SZ_W   = (size_t)9 * 256 * 64 * 2;         // 294912
static constexpr size_t SZ_PBLK = (size_t)4 * 128 * 64 * 4;        // 131072

static constexpr size_t B_XCL = 0;                                 // also r2 (aliased)
static constexpr size_t B_R   = B_XCL + SZ_XCL;
static constexpr size_t B_W1T = B_R + 4 * SZ_XCL;                  // 134.2 MB of r
static constexpr size_t B_W2T = B_W1T + SZ_W;
static constexpr size_t B_WBT = B_W2T + SZ_W;
static constexpr size_t B_DSC = B_WBT + SZ_W;
static constexpr size_t B_BB  = B_DSC + 256;
static constexpr size_t B_GT  = B_BB + 1024;
static constexpr size_t B_PBLK = B_GT + 1024;
static constexpr size_t WS_BIG = B_PBLK + SZ_PBLK;

extern "C" void kernel_launch(void* const* d_in, const int* in_sizes, int n_in,
                              void* d_out, int out_size, void* d_ws, size_t ws_size,
                              hipStream_t stream) {
  (void)in_sizes; (void)n_in; (void)out_size;
  if (ws_size < WS_BIG) return;  // ~169 MB scratch required (harness provides it)

  const float* x     = (const float*)d_in[0];
  const float* scale = (const float*)d_in[1];
  const float* v1    = (const float*)d_in[2];
  const float* g1    = (const float*)d_in[3];
  const float* b1    = (const float*)d_in[4];
  const float* v2    = (const float*)d_in[5];
  const float* g2    = (const float*)d_in[6];
  const float* b2    = (const float*)d_in[7];
  const float* dyn_v = (const float*)d_in[8];
  const float* dyn_g = (const float*)d_in[9];
  const float* dyn_b = (const float*)d_in[10];
  const float* att_w = (const float*)d_in[11];
  const float* att_b = (const float*)d_in[12];
  const float* se_w1 = (const float*)d_in[13];
  const float* se_w2 = (const float*)d_in[14];
  float* out = (float*)d_out;

  char* ws = (char*)d_ws;
  unsigned short* xcl  = (unsigned short*)(ws + B_XCL);
  unsigned short* rbuf = (unsigned short*)(ws + B_R);
  unsigned short* r2   = (unsigned short*)(ws + B_XCL);  // aliases dead xcl
  unsigned short* w1t  = (unsigned short*)(ws + B_W1T);
  unsigned short* w2t  = (unsigned short*)(ws + B_W2T);
  unsigned short* wbt  = (unsigned short*)(ws + B_WBT);
  float* dscale = (float*)(ws + B_DSC);
  float* bias_b = (float*)(ws + B_BB);
  float* gate   = (float*)(ws + B_GT);
  float* pblk   = (float*)(ws + B_PBLK);

  xpose_k<<<dim3(4, 256, 4), 256, 0, stream>>>(x, xcl);
  wnorm_k<256, 64><<<256, 256, 0, stream>>>(v1, g1, w1t);
  wnorm_k<64, 256><<<64, 256, 0, stream>>>(v2, g2, w2t);
  dynnorm_k<<<4, 256, 0, stream>>>(dyn_v, dyn_g, dscale);
  mix_k<<<256, 256, 0, stream>>>(scale, att_w, att_b, dyn_v, dyn_b, dscale, wbt, bias_b);

  // 1-D grids, all divisible by 8 (bijective XCD swizzle)
  conv3x3_mfma<64, 256, 256, true, false><<<2048, 256, 0, stream>>>(
      xcl, w1t, b1, rbuf, nullptr, nullptr);
  conv3x3_mfma<256, 64, 64, false, false><<<512, 256, 0, stream>>>(
      rbuf, w2t, b2, r2, nullptr, nullptr);
  conv3x3_mfma<64, 64, 64, false, true><<<512, 256, 0, stream>>>(
      r2, wbt, bias_b, nullptr, out, pblk);

  gate_k<<<4, 256, 0, stream>>>(pblk, se_w1, se_w2, gate);
  final_k<<<16384, 256, 0, stream>>>(x, gate, out);
}

// Round 7
// 356.820 us; speedup vs baseline: 1.8492x; 1.2131x over previous
//
#include <hip/hip_runtime.h>

typedef __attribute__((ext_vector_type(8))) short short8;
typedef __attribute__((ext_vector_type(4))) float f32x4;

#define HH 256
#define WW 256

__device__ inline unsigned int f2bf(float x) {
  unsigned int u = __float_as_uint(x);
  return (u + 0x7fffu + ((u >> 16) & 1u)) >> 16;   // RTNE truncation to bf16
}
__device__ inline unsigned int pack2(float a, float b) {
  return f2bf(a) | (f2bf(b) << 16);
}

// ---------------- transpose x (fp32 NCHW) -> xcl bf16 [B][H][W][64] ----------------
__global__ __launch_bounds__(256) void xpose_k(const float* __restrict__ x,
                                               unsigned short* __restrict__ xcl) {
  const int t = threadIdx.x;
  const int ci = t & 63;
  const int wv = t >> 6;
  const int x0 = blockIdx.x * 64;
  const int y  = blockIdx.y;
  const int b  = blockIdx.z;
  const float* src = x + ((size_t)(b * 64 + ci) * HH + y) * WW + x0 + wv;
  unsigned short* dst = xcl + ((size_t)(b * HH + y) * WW + x0 + wv) * 64 + ci;
#pragma unroll
  for (int k = 0; k < 16; ++k)
    dst[(size_t)k * 4 * 64] = (unsigned short)f2bf(src[4 * k]);
}

// ---------------- weight norm -> [tap][co][ci] bf16 ----------------
template <int COUT, int CINK>
__global__ __launch_bounds__(256) void wnorm_k(const float* __restrict__ v,
                                               const float* __restrict__ g,
                                               unsigned short* __restrict__ out) {
  constexpr int N = CINK * 9;
  const int co = blockIdx.x, t = threadIdx.x;
  const float* vb = v + (size_t)co * N;
  float s = 0.f;
  for (int i = t; i < N; i += 256) { float a = vb[i]; s += a * a; }
  for (int off = 32; off > 0; off >>= 1) s += __shfl_xor(s, off, 64);
  __shared__ float red[4];
  if ((t & 63) == 0) red[t >> 6] = s;
  __syncthreads();
  const float tot = red[0] + red[1] + red[2] + red[3];
  const float sc = g[co] / sqrtf(tot);
  for (int i = t; i < N; i += 256) {
    int ci = i / 9, tap = i - 9 * (i / 9);
    out[((size_t)tap * COUT + co) * CINK + ci] = (unsigned short)f2bf(vb[i] * sc);
  }
}

// ---------------- dyn bank norms ----------------
__global__ __launch_bounds__(256) void dynnorm_k(const float* __restrict__ dyn_v,
                                                 const float* __restrict__ dyn_g,
                                                 float* __restrict__ dscale) {
  const int k = blockIdx.x, t = threadIdx.x;
  const float* vb = dyn_v + (size_t)k * 36864;
  float s = 0.f;
  for (int i = t; i < 36864; i += 256) { float a = vb[i]; s += a * a; }
  for (int off = 32; off > 0; off >>= 1) s += __shfl_xor(s, off, 64);
  __shared__ float red[4];
  if ((t & 63) == 0) red[t >> 6] = s;
  __syncthreads();
  if (t == 0) dscale[k] = dyn_g[k] / sqrtf(red[0] + red[1] + red[2] + red[3]);
}

// ---------------- per-sample mixed dyn weights + bias; zero the zero-page ----------------
__global__ __launch_bounds__(256) void mix_k(const float* __restrict__ scale,
                                             const float* __restrict__ att_w,
                                             const float* __restrict__ att_b,
                                             const float* __restrict__ dyn_v,
                                             const float* __restrict__ dyn_b,
                                             const float* __restrict__ dscale,
                                             unsigned short* __restrict__ wbt,
                                             float* __restrict__ bias_b,
                                             float* __restrict__ zp) {
  const int blk = blockIdx.x;
  const int b = blk >> 6, co = blk & 63;
  const int t = threadIdx.x;
  float att[4], wsc[4];
  const float sc = scale[b];
  float mx = -1e30f;
#pragma unroll
  for (int k = 0; k < 4; ++k) { att[k] = sc * att_w[k] + att_b[k]; mx = fmaxf(mx, att[k]); }
  float den = 0.f;
#pragma unroll
  for (int k = 0; k < 4; ++k) { att[k] = expf(att[k] - mx); den += att[k]; }
#pragma unroll
  for (int k = 0; k < 4; ++k) { att[k] /= den; wsc[k] = att[k] * dscale[k]; }
  for (int i = t; i < 576; i += 256) {
    int ci = i / 9, tap = i - 9 * (i / 9);
    float w = 0.f;
#pragma unroll
    for (int k = 0; k < 4; ++k)
      w += wsc[k] * dyn_v[(((size_t)k * 64 + co) * 64 + ci) * 9 + tap];
    wbt[(((size_t)b * 9 + tap) * 64 + co) * 64 + ci] = (unsigned short)f2bf(w);
  }
  if (t == 0) {
    float bb = 0.f;
#pragma unroll
    for (int k = 0; k < 4; ++k) bb += att[k] * dyn_b[k * 64 + co];
    bias_b[blk] = bb;
  }
  if (blk == 0) zp[t] = 0.f;  // 1 KB zero page (covers ch*32 walk for all NCH)
}

// ---------------- MFMA 3x3 conv v7: full global_load_lds staging + dx-outer compute ----
// Block: 64co x 16rows x 32cols; wave = m4(64co) x (4r x 2colhalf); ci-chunk 32.
// Input halo 18x34 px x 32ci bf16 (2448 slots x 16B = 39168 B), logical reader byte:
//   byt(px,g) = (px>>1)*128 + ((g*16 + (px&1)*64) ^ (((px>>1)&7)<<4))
// Staged via global_load_lds with LINEAR dest (slot u at byte u*16) and the INVERSE
// swizzle applied to the per-lane GLOBAL source (rule-21 involution):
//   pair=u>>3; s=((u&7)*16)^((pair&7)<<4); parity=s>>6; g=(s>>4)&3; px=2*pair+parity
// A panel [tap][g][co] (2304 slots x 16B = 36864 B), linear: slot = tap*256+g*64+co;
// staged via global_load_lds (conflict-free writes by construction).
// Compute is dx-outer: A[3dy][4m] held in regs; each B fragment read ONCE (36/chunk).
template <int CIN, int COUT, int OSTR, bool RELU, bool DYN>
__global__ __launch_bounds__(256, 2) void conv3x3_mfma(const unsigned short* __restrict__ in_cl,
                                                       const unsigned short* __restrict__ wt,
                                                       const float* __restrict__ bias,
                                                       unsigned short* __restrict__ out_cl,
                                                       float* __restrict__ y_out,
                                                       float* __restrict__ pblk,
                                                       const float* __restrict__ zp) {
  constexpr int CO_TILES = COUT / 64;
  constexpr int NCH = CIN / 32;
  constexpr int NSLOT = 612 * 4;  // 2448 input slots
  const int tid = threadIdx.x;
  const int lane = tid & 63;
  const int wv = tid >> 6;
  const int l15 = lane & 15;
  const int lg = lane >> 4;

  // ---- XCD-aware swizzle (bijective: gridDim.x % 8 == 0) ----
  const int wg = (blockIdx.x & 7) * (gridDim.x >> 3) + (blockIdx.x >> 3);
  int tdec = wg;
  const int cot = tdec % CO_TILES; tdec /= CO_TILES;
  const int bx = tdec & 7; tdec >>= 3;
  const int by = tdec & 15; tdec >>= 4;
  const int bz = tdec;

  const int x0 = bx * 32;
  const int y0 = by * 16;
  const int co0 = cot * 64;

  const unsigned short* inb = in_cl + (size_t)bz * HH * WW * CIN;
  const unsigned short* wtb = wt + (DYN ? (size_t)bz * 9 * 64 * 64 : (size_t)0);
  const float* biasb = bias + (DYN ? bz * 64 : 0);
  const unsigned short* zp16 = (const unsigned short*)zp;

  __shared__ unsigned short tile[NSLOT * 8];    // 39168 B input halo
  __shared__ unsigned short atile[2304 * 8];    // 36864 B A panel

  // ---- input staging sources (inverse-swizzled), chunk-0 base ----
  const unsigned short* sptr[10];
  bool sact[10];
#pragma unroll
  for (int k = 0; k < 10; ++k) {
    const int u = k * 256 + tid;
    const int pair = u >> 3;
    const int s = ((u & 7) * 16) ^ ((pair & 7) << 4);
    const int parity = s >> 6;
    const int g = (s >> 4) & 3;
    const int px = 2 * pair + parity;
    const int row = px / 34, col = px - 34 * row;
    const int gy = y0 - 1 + row, gx = x0 - 1 + col;
    sact[k] = (u < NSLOT);
    const bool ok = sact[k] && ((unsigned)gy < (unsigned)HH) && ((unsigned)gx < (unsigned)WW);
    sptr[k] = ok ? (inb + ((size_t)(gy * WW + gx)) * CIN + g * 8) : zp16;
  }

  f32x4 acc[4][8];
#pragma unroll
  for (int m = 0; m < 4; ++m)
#pragma unroll
    for (int n = 0; n < 8; ++n) acc[m][n] = (f32x4){0.f, 0.f, 0.f, 0.f};

#pragma unroll 1
  for (int ch = 0; ch < NCH; ++ch) {
    if (ch) __syncthreads();  // previous chunk's compute done before overwrite
    // ---- stage input halo: 10 global_load_lds rounds (linear dest) ----
#pragma unroll
    for (int k = 0; k < 10; ++k) {
      if (sact[k])
        __builtin_amdgcn_global_load_lds((const void*)(sptr[k] + ch * 32),
                                         (void*)(tile + (size_t)(k * 256 + wv * 64) * 8),
                                         16, 0, 0);
    }
    // ---- stage A panel: 9 global_load_lds rounds (linear dest) ----
#pragma unroll
    for (int k = 0; k < 9; ++k) {
      const int idx = k * 256 + tid;
      const int tap = idx >> 8;
      const int g = (idx >> 6) & 3;
      const int co = idx & 63;
      __builtin_amdgcn_global_load_lds(
          (const void*)(wtb + ((size_t)(tap * COUT + co0 + co) * CIN + ch * 32 + g * 8)),
          (void*)(atile + (size_t)(k * 256 + wv * 64) * 8), 16, 0, 0);
    }
    __syncthreads();  // drains all staging loads

    // ---- compute: dx-outer, A held in regs, each B fragment read once ----
#pragma unroll
    for (int dx = 0; dx < 3; ++dx) {
      short8 Af[3][4];
#pragma unroll
      for (int dy = 0; dy < 3; ++dy)
#pragma unroll
        for (int m = 0; m < 4; ++m)
          Af[dy][m] = *(const short8*)((const char*)atile +
                                       (((dy * 3 + dx) * 4 + lg) * 1024 + (16 * m + l15) * 16));
#pragma unroll
      for (int ch2 = 0; ch2 < 2; ++ch2) {
#pragma unroll
        for (int bi = 0; bi < 6; ++bi) {
          const int px = (4 * wv + bi) * 34 + 16 * ch2 + l15 + dx;
          const int byt = (px >> 1) * 128 + ((lg * 16 + (px & 1) * 64) ^ (((px >> 1) & 7) << 4));
          const short8 Bv = *(const short8*)((const char*)tile + byt);
          const int dy_lo = (bi > 3) ? (bi - 3) : 0;
          const int dy_hi = (bi < 2) ? bi : 2;
          __builtin_amdgcn_s_setprio(1);
#pragma unroll
          for (int dy = 0; dy < 3; ++dy) {
            if (dy < dy_lo || dy > dy_hi) continue;
            const int n = 2 * (bi - dy) + ch2;
#pragma unroll
            for (int m = 0; m < 4; ++m)
              acc[m][n] = __builtin_amdgcn_mfma_f32_16x16x32_bf16(Af[dy][m], Bv, acc[m][n], 0, 0, 0);
          }
          __builtin_amdgcn_s_setprio(0);
        }
      }
    }
  }

  float scol[4][4];
  if (DYN) {
#pragma unroll
    for (int m = 0; m < 4; ++m)
#pragma unroll
      for (int f = 0; f < 4; ++f) scol[m][f] = 0.f;
  }

#pragma unroll
  for (int m = 0; m < 4; ++m) {
    const f32x4 bs = *(const f32x4*)(biasb + co0 + 16 * m + 4 * lg);
#pragma unroll
    for (int n = 0; n < 8; ++n) {
      f32x4 v = acc[m][n] + bs;
      if (RELU) {
        v.x = fmaxf(v.x, 0.f); v.y = fmaxf(v.y, 0.f);
        v.z = fmaxf(v.z, 0.f); v.w = fmaxf(v.w, 0.f);
      }
      const int yy = y0 + 4 * wv + (n >> 1);
      const int xx = x0 + 16 * (n & 1) + l15;
      if (!DYN) {
        uint2 pk;
        pk.x = pack2(v.x, v.y);
        pk.y = pack2(v.z, v.w);
        *(uint2*)(out_cl + (size_t)bz * HH * WW * OSTR +
                  ((size_t)(yy * WW + xx)) * OSTR + co0 + 16 * m + 4 * lg) = pk;
      } else {
        const size_t base = ((size_t)(bz * 64 + 16 * m + 4 * lg) * HH + yy) * WW + xx;
        y_out[base]             = v.x;
        y_out[base + 1 * 65536] = v.y;
        y_out[base + 2 * 65536] = v.z;
        y_out[base + 3 * 65536] = v.w;
        scol[m][0] += v.x; scol[m][1] += v.y; scol[m][2] += v.z; scol[m][3] += v.w;
      }
    }
  }
  if (DYN) {
#pragma unroll
    for (int m = 0; m < 4; ++m)
#pragma unroll
      for (int f = 0; f < 4; ++f) {
        float r = scol[m][f];
        r += __shfl_xor(r, 1, 64);
        r += __shfl_xor(r, 2, 64);
        r += __shfl_xor(r, 4, 64);
        r += __shfl_xor(r, 8, 64);
        scol[m][f] = r;
      }
    __syncthreads();  // tile dead; reuse as fp32 scratch
    float* red = (float*)tile;
    if (l15 == 0) {
#pragma unroll
      for (int m = 0; m < 4; ++m)
#pragma unroll
        for (int f = 0; f < 4; ++f)
          red[wv * 64 + 16 * m + 4 * lg + f] = scol[m][f];
    }
    __syncthreads();
    if (tid < 64) {
      const float s = red[tid] + red[64 + tid] + red[128 + tid] + red[192 + tid];
      pblk[((size_t)bz * 128 + by * 8 + bx) * 64 + tid] = s;
    }
  }
}

// ---------------- SE gate: 4 blocks (one per sample) ----------------
__global__ __launch_bounds__(256) void gate_k(const float* __restrict__ pblk,
                                              const float* __restrict__ se_w1,
                                              const float* __restrict__ se_w2,
                                              float* __restrict__ gate) {
  const int b = blockIdx.x;
  const int t = threadIdx.x;
  const int c = t & 63, part = t >> 6;
  __shared__ float ps[4][64];
  __shared__ float p_s[64], h_s[16];
  float s = 0.f;
  for (int blk = part; blk < 128; blk += 4)
    s += pblk[((size_t)b * 128 + blk) * 64 + c];
  ps[part][c] = s;
  __syncthreads();
  if (t < 64) p_s[t] = (ps[0][t] + ps[1][t] + ps[2][t] + ps[3][t]) * (1.f / 65536.f);
  __syncthreads();
  if (t < 16) {
    float h = 0.f;
    for (int cc = 0; cc < 64; ++cc) h += p_s[cc] * se_w1[t * 64 + cc];
    h_s[t] = fmaxf(h, 0.f);
  }
  __syncthreads();
  if (t < 64) {
    float a = 0.f;
    for (int j = 0; j < 16; ++j) a += h_s[j] * se_w2[t * 16 + j];
    gate[b * 64 + t] = 1.f / (1.f + expf(-a));
  }
}

// ---------------- final: out = x + y*gate (in-place on d_out) ----------------
__global__ __launch_bounds__(256) void final_k(const float* __restrict__ x,
                                               const float* __restrict__ gate,
                                               float* __restrict__ out) {
  const size_t i = ((size_t)blockIdx.x * 256 + threadIdx.x) * 4;
  f32x4 yv = *(f32x4*)(out + i);
  const f32x4 xv = *(const f32x4*)(x + i);
  const float g = gate[(int)(i >> 16)];
  yv = xv + yv * g;
  *(f32x4*)(out + i) = yv;
}

// ---------------- workspace layout (batched) ----------------
static constexpr size_t SZ_XCL = (size_t)4 * 256 * 256 * 64 * 2;   // 33.55 MB
static constexpr size_t SZ_W   = (size_t)9 * 256 * 64 * 2;         // 294912
static constexpr size_t SZ_PBLK = (size_t)4 * 128 * 64 * 4;        // 131072

static constexpr size_t B_XCL = 0;                                 // also r2 (aliased)
static constexpr size_t B_R   = B_XCL + SZ_XCL;
static constexpr size_t B_W1T = B_R + 4 * SZ_XCL;                  // 134.2 MB of r
static constexpr size_t B_W2T = B_W1T + SZ_W;
static constexpr size_t B_WBT = B_W2T + SZ_W;
static constexpr size_t B_DSC = B_WBT + SZ_W;
static constexpr size_t B_BB  = B_DSC + 256;
static constexpr size_t B_GT  = B_BB + 1024;
static constexpr size_t B_ZP  = B_GT + 1024;
static constexpr size_t B_PBLK = B_ZP + 1024;
static constexpr size_t WS_BIG = B_PBLK + SZ_PBLK;

extern "C" void kernel_launch(void* const* d_in, const int* in_sizes, int n_in,
                              void* d_out, int out_size, void* d_ws, size_t ws_size,
                              hipStream_t stream) {
  (void)in_sizes; (void)n_in; (void)out_size;
  if (ws_size < WS_BIG) return;  // ~169 MB scratch required (harness provides it)

  const float* x     = (const float*)d_in[0];
  const float* scale = (const float*)d_in[1];
  const float* v1    = (const float*)d_in[2];
  const float* g1    = (const float*)d_in[3];
  const float* b1    = (const float*)d_in[4];
  const float* v2    = (const float*)d_in[5];
  const float* g2    = (const float*)d_in[6];
  const float* b2    = (const float*)d_in[7];
  const float* dyn_v = (const float*)d_in[8];
  const float* dyn_g = (const float*)d_in[9];
  const float* dyn_b = (const float*)d_in[10];
  const float* att_w = (const float*)d_in[11];
  const float* att_b = (const float*)d_in[12];
  const float* se_w1 = (const float*)d_in[13];
  const float* se_w2 = (const float*)d_in[14];
  float* out = (float*)d_out;

  char* ws = (char*)d_ws;
  unsigned short* xcl  = (unsigned short*)(ws + B_XCL);
  unsigned short* rbuf = (unsigned short*)(ws + B_R);
  unsigned short* r2   = (unsigned short*)(ws + B_XCL);  // aliases dead xcl
  unsigned short* w1t  = (unsigned short*)(ws + B_W1T);
  unsigned short* w2t  = (unsigned short*)(ws + B_W2T);
  unsigned short* wbt  = (unsigned short*)(ws + B_WBT);
  float* dscale = (float*)(ws + B_DSC);
  float* bias_b = (float*)(ws + B_BB);
  float* gate   = (float*)(ws + B_GT);
  float* zp     = (float*)(ws + B_ZP);
  float* pblk   = (float*)(ws + B_PBLK);

  xpose_k<<<dim3(4, 256, 4), 256, 0, stream>>>(x, xcl);
  wnorm_k<256, 64><<<256, 256, 0, stream>>>(v1, g1, w1t);
  wnorm_k<64, 256><<<64, 256, 0, stream>>>(v2, g2, w2t);
  dynnorm_k<<<4, 256, 0, stream>>>(dyn_v, dyn_g, dscale);
  mix_k<<<256, 256, 0, stream>>>(scale, att_w, att_b, dyn_v, dyn_b, dscale, wbt, bias_b, zp);

  // 1-D grids, all divisible by 8 (bijective XCD swizzle)
  conv3x3_mfma<64, 256, 256, true, false><<<2048, 256, 0, stream>>>(
      xcl, w1t, b1, rbuf, nullptr, nullptr, zp);
  conv3x3_mfma<256, 64, 64, false, false><<<512, 256, 0, stream>>>(
      rbuf, w2t, b2, r2, nullptr, nullptr, zp);
  conv3x3_mfma<64, 64, 64, false, true><<<512, 256, 0, stream>>>(
      r2, wbt, bias_b, nullptr, out, pblk, zp);

  gate_k<<<4, 256, 0, stream>>>(pblk, se_w1, se_w2, gate);
  final_k<<<16384, 256, 0, stream>>>(x, gate, out);
}